// Round 3
// baseline (4471.533 us; speedup 1.0000x reference)
//
#include <hip/hip_runtime.h>
#include <math.h>

#define NTHREADS 256
#define IN_C 128
#define HID 64
#define OUT_C 40
#define N_LAYERS 8
#define ALPHA 0.1f
#define BN_EPS 1e-5f

// bf16 helpers (OCP bf16 = top 16 bits of fp32, RNE)
__device__ __forceinline__ float b2f(unsigned short v) {
  return __uint_as_float((unsigned int)v << 16);
}
__device__ __forceinline__ unsigned short f2b(float f) {
  unsigned int u = __float_as_uint(f);
  unsigned int r = (u + 0x7FFFu + ((u >> 16) & 1u)) >> 16;
  return (unsigned short)r;
}

// ---------------- setup kernels ----------------

__global__ void k_zero(int* __restrict__ cnt, float* __restrict__ sumP,
                       float* __restrict__ sumsqP, float* __restrict__ mstat, int n) {
  int i = blockIdx.x * NTHREADS + threadIdx.x;
  if (i < n) cnt[i] = 0;
  if (i < 1024) { sumP[i] = 0.f; sumsqP[i] = 0.f; }
  if (i < 64) mstat[i] = 1.f;                 // identity affine for layer 0
  else if (i < 128) mstat[i] = 0.f;
}

__global__ void k_hist(const int* __restrict__ col, int* __restrict__ cnt, int E) {
  int e = blockIdx.x * NTHREADS + threadIdx.x;
  if (e < E) atomicAdd(&cnt[col[e]], 1);
}

// deg includes the self loop: deg[i] = cnt[i] + 1
__global__ void k_dinv(const int* __restrict__ cnt, float* __restrict__ dinv, int n) {
  int i = blockIdx.x * NTHREADS + threadIdx.x;
  if (i < n) dinv[i] = rsqrtf((float)cnt[i] + 1.0f);
}

// exclusive scan, pass 1
__global__ void k_scan1(const int* __restrict__ cnt, int* __restrict__ offs,
                        int* __restrict__ partials, int n) {
  __shared__ int sh[NTHREADS];
  int t = threadIdx.x, i = blockIdx.x * NTHREADS + t;
  int v = (i < n) ? cnt[i] : 0;
  sh[t] = v;
  __syncthreads();
  int run = v;
  for (int d = 1; d < NTHREADS; d <<= 1) {
    int add = (t >= d) ? sh[t - d] : 0;
    __syncthreads();
    run += add;
    sh[t] = run;
    __syncthreads();
  }
  if (i < n) offs[i] = run - v;
  if (t == NTHREADS - 1) partials[blockIdx.x] = run;
}

// pass 2: scan the (<=512) block totals
__global__ void k_scan2(int* __restrict__ partials, int nb) {
  __shared__ int sh[512];
  int t = threadIdx.x;
  int v = (t < nb) ? partials[t] : 0;
  sh[t] = v;
  __syncthreads();
  int run = v;
  for (int d = 1; d < 512; d <<= 1) {
    int add = (t >= d) ? sh[t - d] : 0;
    __syncthreads();
    run += add;
    sh[t] = run;
    __syncthreads();
  }
  if (t < nb) partials[t] = run - v;
}

// pass 3: add block offsets; init fill cursors; set offs[n]=E
__global__ void k_scan3(int* __restrict__ offs, int* __restrict__ cur,
                        const int* __restrict__ partials, int n, int E) {
  int i = blockIdx.x * NTHREADS + threadIdx.x;
  if (i < n) {
    int v = offs[i] + partials[i >> 8];
    offs[i] = v;
    cur[i] = v;
  }
  if (i == 0) offs[n] = E;
}

// CSR fill grouped by destination; packs {src, dinv[src]} into one 8B record
__global__ void k_fill(const int* __restrict__ row, const int* __restrict__ col,
                       const float* __restrict__ dinv, int* __restrict__ cur,
                       int2* __restrict__ ew, int E) {
  int e = blockIdx.x * NTHREADS + threadIdx.x;
  if (e < E) {
    int cl = col[e];
    int rw = row[e];
    int pos = atomicAdd(&cur[cl], 1);
    ew[pos] = make_int2(rw, __float_as_int(dinv[rw]));
  }
}

// ---------------- h0 = relu(x @ W0 + b0), stored bf16 ----------------
__global__ __launch_bounds__(NTHREADS) void k_gemm0(
    const float* __restrict__ x, const float* __restrict__ W0,
    const float* __restrict__ b0, unsigned short* __restrict__ h0, int n) {
  __shared__ float Ws[IN_C * HID];   // 32 KB
  __shared__ float xs[8 * IN_C];     // 4 KB
  int t = threadIdx.x;
  for (int m = t; m < IN_C * HID / 4; m += NTHREADS)
    ((float4*)Ws)[m] = ((const float4*)W0)[m];
  int gi = blockIdx.x * 256 + t;
  if (gi * 4 < n * IN_C) ((float4*)xs)[t] = ((const float4*)x)[gi];
  __syncthreads();
  int ty = t >> 6, c = t & 63;
  int r0 = blockIdx.x * 8 + ty * 2;
  float bias = b0[c];
  float acc0 = bias, acc1 = bias;
  const float4* xr0 = (const float4*)(xs + (ty * 2) * IN_C);
  const float4* xr1 = (const float4*)(xs + (ty * 2 + 1) * IN_C);
  for (int kk = 0; kk < IN_C / 4; kk++) {
    float4 a0 = xr0[kk], a1 = xr1[kk];
    int k = kk * 4;
    float w0 = Ws[(k + 0) * HID + c], w1 = Ws[(k + 1) * HID + c];
    float w2 = Ws[(k + 2) * HID + c], w3 = Ws[(k + 3) * HID + c];
    acc0 += a0.x * w0 + a0.y * w1 + a0.z * w2 + a0.w * w3;
    acc1 += a1.x * w0 + a1.y * w1 + a1.z * w2 + a1.w * w3;
  }
  acc0 = fmaxf(acc0, 0.f);
  acc1 = fmaxf(acc1, 0.f);
  if (r0 < n)     h0[((unsigned)r0 << 6) | c] = f2b(acc0);
  if (r0 + 1 < n) h0[(((unsigned)r0 + 1) << 6) | c] = f2b(acc1);
}

// ---------------- fused layer ----------------
// Reads bf16 buffer B, applies folded BN affine (scale/shift per channel) + relu
// on the fly -> gather + residual + s@convW + BN-stats. Writes raw bf16 s.
// block = 4 waves, wave handles 4 nodes/iter, lane = channel. ss is wave-private
// (no in-loop barriers). 8-wide edge unroll for MLP.
__global__ __launch_bounds__(NTHREADS, 3) void k_layer(
    const unsigned short* __restrict__ B, const unsigned short* __restrict__ h0,
    const float* __restrict__ mstat, const float* __restrict__ dinv,
    const int* __restrict__ offs, const int2* __restrict__ ew,
    const float* __restrict__ Wl, unsigned short* __restrict__ sout,
    float* __restrict__ sumP, float* __restrict__ sumsqP, float beta, int n) {
  __shared__ float Wsh[HID * HID];   // 16 KB
  __shared__ float ss[16 * HID];     // 4 KB (wave-private quarters)
  __shared__ float red[2 * NTHREADS];
  int t = threadIdx.x;
  for (int m = t; m < HID * HID / 4; m += NTHREADS)
    ((float4*)Wsh)[m] = ((const float4*)Wl)[m];
  int wid = t >> 6, c = t & 63;
  float sc = mstat[c], sh = mstat[64 + c];
  __syncthreads();
  float lsum = 0.f, lsumsq = 0.f;
  int stride = gridDim.x * 16;
  for (int base = blockIdx.x * 16; base < n; base += stride) {
    int i0 = base + wid * 4;
    float sv[4];
    for (int r = 0; r < 4; r++) {
      int i = i0 + r;
      float sval = 0.f;
      if (i < n) {
        float di = dinv[i];
        float hvs = fmaxf(fmaf(b2f(B[((unsigned)i << 6) | c]), sc, sh), 0.f);
        float acc = di * hvs;                        // self loop
        int jb = offs[i], je = offs[i + 1];
        int j = jb;
        for (; j + 8 <= je; j += 8) {
          int2 e0 = ew[j + 0], e1 = ew[j + 1], e2 = ew[j + 2], e3 = ew[j + 3];
          int2 e4 = ew[j + 4], e5 = ew[j + 5], e6 = ew[j + 6], e7 = ew[j + 7];
          unsigned short v0 = B[((unsigned)e0.x << 6) | c];
          unsigned short v1 = B[((unsigned)e1.x << 6) | c];
          unsigned short v2 = B[((unsigned)e2.x << 6) | c];
          unsigned short v3 = B[((unsigned)e3.x << 6) | c];
          unsigned short v4 = B[((unsigned)e4.x << 6) | c];
          unsigned short v5 = B[((unsigned)e5.x << 6) | c];
          unsigned short v6 = B[((unsigned)e6.x << 6) | c];
          unsigned short v7 = B[((unsigned)e7.x << 6) | c];
          acc += __int_as_float(e0.y) * fmaxf(fmaf(b2f(v0), sc, sh), 0.f);
          acc += __int_as_float(e1.y) * fmaxf(fmaf(b2f(v1), sc, sh), 0.f);
          acc += __int_as_float(e2.y) * fmaxf(fmaf(b2f(v2), sc, sh), 0.f);
          acc += __int_as_float(e3.y) * fmaxf(fmaf(b2f(v3), sc, sh), 0.f);
          acc += __int_as_float(e4.y) * fmaxf(fmaf(b2f(v4), sc, sh), 0.f);
          acc += __int_as_float(e5.y) * fmaxf(fmaf(b2f(v5), sc, sh), 0.f);
          acc += __int_as_float(e6.y) * fmaxf(fmaf(b2f(v6), sc, sh), 0.f);
          acc += __int_as_float(e7.y) * fmaxf(fmaf(b2f(v7), sc, sh), 0.f);
        }
        for (; j < je; j++) {
          int2 e = ew[j];
          unsigned short v = B[((unsigned)e.x << 6) | c];
          acc += __int_as_float(e.y) * fmaxf(fmaf(b2f(v), sc, sh), 0.f);
        }
        float agg = di * acc;
        sval = (1.f - ALPHA) * agg + ALPHA * b2f(h0[((unsigned)i << 6) | c]);
      }
      sv[r] = sval;
      ss[(((wid << 2) + r) << 6) | c] = sval;   // wave-private transpose tile
    }
    // conv phase (wave-private; compiler inserts lgkm waits, no barrier needed)
    float ta0 = 0.f, ta1 = 0.f, ta2 = 0.f, ta3 = 0.f;
    const float4* s0 = (const float4*)(ss + ((wid * 4 + 0) << 6));
    const float4* s1 = (const float4*)(ss + ((wid * 4 + 1) << 6));
    const float4* s2 = (const float4*)(ss + ((wid * 4 + 2) << 6));
    const float4* s3 = (const float4*)(ss + ((wid * 4 + 3) << 6));
    for (int kk = 0; kk < HID / 4; kk++) {
      int k = kk * 4;
      float w0 = Wsh[(k + 0) * HID + c], w1 = Wsh[(k + 1) * HID + c];
      float w2 = Wsh[(k + 2) * HID + c], w3 = Wsh[(k + 3) * HID + c];
      float4 a;
      a = s0[kk]; ta0 += a.x * w0 + a.y * w1 + a.z * w2 + a.w * w3;
      a = s1[kk]; ta1 += a.x * w0 + a.y * w1 + a.z * w2 + a.w * w3;
      a = s2[kk]; ta2 += a.x * w0 + a.y * w1 + a.z * w2 + a.w * w3;
      a = s3[kk]; ta3 += a.x * w0 + a.y * w1 + a.z * w2 + a.w * w3;
    }
    float ta[4] = {ta0, ta1, ta2, ta3};
#pragma unroll
    for (int r = 0; r < 4; r++) {
      int i = i0 + r;
      if (i < n) {
        float s2v = (1.f - beta) * sv[r] + beta * ta[r];
        sout[((unsigned)i << 6) | c] = f2b(s2v);
        lsum += s2v;
        lsumsq += s2v * s2v;
      }
    }
  }
  red[t] = lsum;
  red[NTHREADS + t] = lsumsq;
  __syncthreads();
  if (wid == 0) {
    float a = red[c] + red[64 + c] + red[128 + c] + red[192 + c];
    float b = red[NTHREADS + c] + red[NTHREADS + 64 + c] +
              red[NTHREADS + 128 + c] + red[NTHREADS + 192 + c];
    atomicAdd(&sumP[c * 16], a);
    atomicAdd(&sumsqP[c * 16], b);
  }
}

// folded BN affine: scale = gamma*rsqrt(var+eps), shift = beta - mu*scale.
// Also resets accumulators for the next layer.
__global__ void k_finalize(float* __restrict__ sumP, float* __restrict__ sumsqP,
                           const float* __restrict__ gamma_l,
                           const float* __restrict__ beta_l,
                           float* __restrict__ mstat, int n) {
  int c = threadIdx.x;  // 64 threads
  float s = sumP[c * 16], sq = sumsqP[c * 16];
  float mu = s / (float)n;
  float var = sq / (float)n - mu * mu;
  float scale = gamma_l[c] * rsqrtf(var + BN_EPS);
  mstat[c] = scale;
  mstat[64 + c] = beta_l[c] - mu * scale;
  sumP[c * 16] = 0.f;
  sumsqP[c * 16] = 0.f;
}

// out = relu(affine(s7)) @ W_out + b_out
__global__ __launch_bounds__(NTHREADS) void k_out(
    const unsigned short* __restrict__ s7, const float* __restrict__ mstat,
    const float* __restrict__ Wout, const float* __restrict__ bout,
    float* __restrict__ out, int n) {
  __shared__ float Ws[HID * OUT_C];
  __shared__ float bs[OUT_C];
  __shared__ float scs[HID], shs[HID];
  int t = threadIdx.x;
  for (int m = t; m < HID * OUT_C; m += NTHREADS) Ws[m] = Wout[m];
  if (t < OUT_C) bs[t] = bout[t];
  if (t < HID) { scs[t] = mstat[t]; shs[t] = mstat[64 + t]; }
  __syncthreads();
  int idx = blockIdx.x * NTHREADS + t;
  if (idx < n * OUT_C) {
    int row = idx / OUT_C;
    int c = idx - row * OUT_C;
    float acc = bs[c];
    const uint4* r4 = (const uint4*)(s7 + ((size_t)row << 6));
#pragma unroll
    for (int kk = 0; kk < 8; kk++) {
      uint4 p = r4[kk];
      int k = kk * 8;
      unsigned int pw[4] = {p.x, p.y, p.z, p.w};
#pragma unroll
      for (int q = 0; q < 4; q++) {
        float lo = __uint_as_float(pw[q] << 16);
        float hi = __uint_as_float(pw[q] & 0xFFFF0000u);
        float hlo = fmaxf(fmaf(lo, scs[k + 2 * q], shs[k + 2 * q]), 0.f);
        float hhi = fmaxf(fmaf(hi, scs[k + 2 * q + 1], shs[k + 2 * q + 1]), 0.f);
        acc += hlo * Ws[(k + 2 * q) * OUT_C + c] + hhi * Ws[(k + 2 * q + 1) * OUT_C + c];
      }
    }
    out[idx] = acc;
  }
}

// ---------------- host ----------------

extern "C" void kernel_launch(void* const* d_in, const int* in_sizes, int n_in,
                              void* d_out, int out_size, void* d_ws, size_t ws_size,
                              hipStream_t stream) {
  const float* x = (const float*)d_in[0];
  const int* ei = (const int*)d_in[1];
  const float* W0 = (const float*)d_in[2];
  const float* b0 = (const float*)d_in[3];
  const float* convW = (const float*)d_in[4];
  const float* bn_gamma = (const float*)d_in[5];
  const float* bn_beta = (const float*)d_in[6];
  const float* W_out = (const float*)d_in[7];
  const float* b_out = (const float*)d_in[8];
  float* out = (float*)d_out;

  int n = in_sizes[0] / IN_C;   // 100000
  int E = in_sizes[1] / 2;      // 1600000
  const int* row = ei;
  const int* col = ei + E;

  char* w = (char*)d_ws;
  auto alloc = [&](size_t bytes) {
    char* p = w;
    w += (bytes + 255) & ~(size_t)255;
    return p;
  };
  float* dinv    = (float*)alloc((size_t)n * 4);
  int*   cnt     = (int*)alloc((size_t)n * 4);
  int*   offs    = (int*)alloc((size_t)(n + 1) * 4);
  int*   cur     = (int*)alloc((size_t)n * 4);
  int*   partials= (int*)alloc(512 * 4);
  int2*  ew      = (int2*)alloc((size_t)E * 8);
  unsigned short* h0b = (unsigned short*)alloc((size_t)n * HID * 2);
  unsigned short* s_a = (unsigned short*)alloc((size_t)n * HID * 2);
  unsigned short* s_b = (unsigned short*)alloc((size_t)n * HID * 2);
  float* sumP    = (float*)alloc(1024 * 4);
  float* sumsqP  = (float*)alloc(1024 * 4);
  float* mstat   = (float*)alloc(128 * 4);

  int gN = (n + NTHREADS - 1) / NTHREADS;   // 391
  int gE = (E + NTHREADS - 1) / NTHREADS;   // 6250

  k_zero<<<gN, NTHREADS, 0, stream>>>(cnt, sumP, sumsqP, mstat, n);
  k_hist<<<gE, NTHREADS, 0, stream>>>(col, cnt, E);
  k_dinv<<<gN, NTHREADS, 0, stream>>>(cnt, dinv, n);
  k_scan1<<<gN, NTHREADS, 0, stream>>>(cnt, offs, partials, n);
  k_scan2<<<1, 512, 0, stream>>>(partials, gN);
  k_scan3<<<gN, NTHREADS, 0, stream>>>(offs, cur, partials, n, E);
  k_fill<<<gE, NTHREADS, 0, stream>>>(row, col, dinv, cur, ew, E);

  k_gemm0<<<(n + 7) / 8, NTHREADS, 0, stream>>>(x, W0, b0, h0b, n);

  const unsigned short* Bin = h0b;
  for (int l = 0; l < N_LAYERS; l++) {
    float beta = logf(0.5f / (float)(l + 1) + 1.0f);
    unsigned short* So = (l & 1) ? s_b : s_a;
    k_layer<<<1024, NTHREADS, 0, stream>>>(Bin, h0b, mstat, dinv, offs, ew,
                                           convW + (size_t)l * HID * HID, So,
                                           sumP, sumsqP, beta, n);
    k_finalize<<<1, 64, 0, stream>>>(sumP, sumsqP, bn_gamma + l * HID,
                                     bn_beta + l * HID, mstat, n);
    Bin = So;
  }

  k_out<<<((size_t)n * OUT_C + NTHREADS - 1) / NTHREADS, NTHREADS, 0, stream>>>(
      Bin, mstat, W_out, b_out, out, n);
}